// Round 8
// baseline (1450.885 us; speedup 1.0000x reference)
//
#include <hip/hip_runtime.h>

#define BLOCK 512    // 8 waves of 64
#define NAMPS 64     // amps per thread (128 VGPRs of state)
#define CHUNK 32     // regs per staging phase for wave-exchange ops (128 KB buffer)

// ---------- state: 64 named float2 members, compile-time indexed ----------
struct St {
  float2 a0,a1,a2,a3,a4,a5,a6,a7,a8,a9,a10,a11,a12,a13,a14,a15,
         a16,a17,a18,a19,a20,a21,a22,a23,a24,a25,a26,a27,a28,a29,a30,a31,
         a32,a33,a34,a35,a36,a37,a38,a39,a40,a41,a42,a43,a44,a45,a46,a47,
         a48,a49,a50,a51,a52,a53,a54,a55,a56,a57,a58,a59,a60,a61,a62,a63;
  template<int I> __device__ __forceinline__ float2& g(){
    if constexpr (I==0) return a0;   else if constexpr (I==1) return a1;
    else if constexpr (I==2) return a2;   else if constexpr (I==3) return a3;
    else if constexpr (I==4) return a4;   else if constexpr (I==5) return a5;
    else if constexpr (I==6) return a6;   else if constexpr (I==7) return a7;
    else if constexpr (I==8) return a8;   else if constexpr (I==9) return a9;
    else if constexpr (I==10) return a10; else if constexpr (I==11) return a11;
    else if constexpr (I==12) return a12; else if constexpr (I==13) return a13;
    else if constexpr (I==14) return a14; else if constexpr (I==15) return a15;
    else if constexpr (I==16) return a16; else if constexpr (I==17) return a17;
    else if constexpr (I==18) return a18; else if constexpr (I==19) return a19;
    else if constexpr (I==20) return a20; else if constexpr (I==21) return a21;
    else if constexpr (I==22) return a22; else if constexpr (I==23) return a23;
    else if constexpr (I==24) return a24; else if constexpr (I==25) return a25;
    else if constexpr (I==26) return a26; else if constexpr (I==27) return a27;
    else if constexpr (I==28) return a28; else if constexpr (I==29) return a29;
    else if constexpr (I==30) return a30; else if constexpr (I==31) return a31;
    else if constexpr (I==32) return a32; else if constexpr (I==33) return a33;
    else if constexpr (I==34) return a34; else if constexpr (I==35) return a35;
    else if constexpr (I==36) return a36; else if constexpr (I==37) return a37;
    else if constexpr (I==38) return a38; else if constexpr (I==39) return a39;
    else if constexpr (I==40) return a40; else if constexpr (I==41) return a41;
    else if constexpr (I==42) return a42; else if constexpr (I==43) return a43;
    else if constexpr (I==44) return a44; else if constexpr (I==45) return a45;
    else if constexpr (I==46) return a46; else if constexpr (I==47) return a47;
    else if constexpr (I==48) return a48; else if constexpr (I==49) return a49;
    else if constexpr (I==50) return a50; else if constexpr (I==51) return a51;
    else if constexpr (I==52) return a52; else if constexpr (I==53) return a53;
    else if constexpr (I==54) return a54; else if constexpr (I==55) return a55;
    else if constexpr (I==56) return a56; else if constexpr (I==57) return a57;
    else if constexpr (I==58) return a58; else if constexpr (I==59) return a59;
    else if constexpr (I==60) return a60; else if constexpr (I==61) return a61;
    else if constexpr (I==62) return a62; else return a63;
  }
};

__device__ __forceinline__ float2 cmadd2(float2 u, float2 a, float2 v, float2 b){
  return make_float2(u.x*a.x - u.y*a.y + v.x*b.x - v.y*b.y,
                     u.x*a.y + u.y*a.x + v.x*b.y + v.y*b.x);
}

// ================= template-recursive gate bodies (all indices compile-time) =================

// ---- rotation on local k-bit BL (0..5) ----
template<int BL, int K>
__device__ __forceinline__ void rot_local_impl(St& st, float2 u00, float2 u01, float2 u10, float2 u11){
  if constexpr (K < NAMPS){
    if constexpr (!(K & (1<<BL))){
      constexpr int K1 = K | (1<<BL);
      float2 x0 = st.g<K>(), x1 = st.g<K1>();
      st.g<K>()  = cmadd2(u00, x0, u01, x1);
      st.g<K1>() = cmadd2(u10, x0, u11, x1);
    }
    rot_local_impl<BL, K+1>(st, u00, u01, u10, u11);
  }
}
template<int BL>
__device__ __forceinline__ void rot_local(St& st, const float* u){
  float2 u00 = make_float2(u[0],u[1]), u01 = make_float2(u[2],u[3]);
  float2 u10 = make_float2(u[4],u[5]), u11 = make_float2(u[6],u[7]);
  rot_local_impl<BL, 0>(st, u00, u01, u10, u11);
}

// ---- LDS staging helpers (compile-time chunk index) ----
template<int Base, int K>
__device__ __forceinline__ void stw_impl(St& st, float2* xbuf, int t){
  if constexpr (K < CHUNK){
    xbuf[K*BLOCK + t] = st.g<Base + K>();
    stw_impl<Base, K+1>(st, xbuf, t);
  }
}
template<int Base, int K>
__device__ __forceinline__ void ldr_rot_impl(St& st, const float2* xbuf, int partner, float2 ua, float2 ub){
  if constexpr (K < CHUNK){
    float2 p = xbuf[K*BLOCK + partner];
    float2 A = st.g<Base + K>();
    st.g<Base + K>() = cmadd2(ua, A, ub, p);
    ldr_rot_impl<Base, K+1>(st, xbuf, partner, ua, ub);
  }
}
template<int Base, int K>
__device__ __forceinline__ void ldr_mov_impl(St& st, const float2* xbuf, int src){
  if constexpr (K < CHUNK){
    st.g<Base + K>() = xbuf[K*BLOCK + src];
    ldr_mov_impl<Base, K+1>(st, xbuf, src);
  }
}

// ---- rotation on wave bit WB (0..2): LDS pair exchange, reg-phased ----
template<int WB>
__device__ __forceinline__ void rot_wave(St& st, const float* u, int t, float2* xbuf){
  const int partner = t ^ (64 << WB);
  const int bit = (t >> (6 + WB)) & 1;
  float2 u00 = make_float2(u[0],u[1]), u01 = make_float2(u[2],u[3]);
  float2 u10 = make_float2(u[4],u[5]), u11 = make_float2(u[6],u[7]);
  float2 ua = bit ? u11 : u00;
  float2 ub = bit ? u10 : u01;
  __syncthreads();                       // prior xbuf readers done
  stw_impl<0, 0>(st, xbuf, t);
  __syncthreads();
  ldr_rot_impl<0, 0>(st, xbuf, partner, ua, ub);
  __syncthreads();
  stw_impl<32, 0>(st, xbuf, t);
  __syncthreads();
  ldr_rot_impl<32, 0>(st, xbuf, partner, ua, ub);
}

// ---- X1: lane-bits <-> reg-bits transpose (wave-local; two 4-wave groups) ----
// write: row = own lane L, col = K^L (XOR swizzle, bijective per row)
// read:  row = K,          col = L^K  -> value of old (lane=K, reg=L): exact lane/reg swap
template<int K>
__device__ __forceinline__ void x1_w_impl(St& st, float2* xbuf, int W3, int L){
  if constexpr (K < NAMPS){
    xbuf[W3*4096 + L*64 + ((K ^ L) & 63)] = st.g<K>();
    x1_w_impl<K+1>(st, xbuf, W3, L);
  }
}
template<int K>
__device__ __forceinline__ void x1_r_impl(St& st, const float2* xbuf, int W3, int L){
  if constexpr (K < NAMPS){
    st.g<K>() = xbuf[W3*4096 + K*64 + ((L ^ K) & 63)];
    x1_r_impl<K+1>(st, xbuf, W3, L);
  }
}
__device__ __forceinline__ void x1_transpose(St& st, int t, float2* xbuf){
  const int W = t >> 6, L = t & 63, W3 = W & 3;
  const bool grpA = (W < 4);
  __syncthreads();
  if (grpA)  x1_w_impl<0>(st, xbuf, W3, L);
  __syncthreads();
  if (grpA)  x1_r_impl<0>(st, xbuf, W3, L);
  __syncthreads();
  if (!grpA) x1_w_impl<0>(st, xbuf, W3, L);
  __syncthreads();
  if (!grpA) x1_r_impl<0>(st, xbuf, W3, L);
}

// ---- fused CNOT wave chain (c=w2,t=w1 then c=w1',t=w0): pure wave perm, reg-phased ----
__device__ __forceinline__ void cnot_wavechain(St& st, int t, float2* xbuf){
  const int wave = t >> 6, lane = t & 63;
  const int src = ((wave ^ ((wave >> 1) & 3)) << 6) | lane;
  __syncthreads();
  stw_impl<0, 0>(st, xbuf, t);
  __syncthreads();
  ldr_mov_impl<0, 0>(st, xbuf, src);
  __syncthreads();
  stw_impl<32, 0>(st, xbuf, t);
  __syncthreads();
  ldr_mov_impl<32, 0>(st, xbuf, src);
}

// ---- fused CNOT lane chain (q2..q7): one shuffle sweep; src = gray(lane) ^ (w0<<5) ----
template<int K>
__device__ __forceinline__ void lanechain_impl(St& st, int src){
  if constexpr (K < NAMPS){
    float2 A = st.g<K>();
    float2 p;
    p.x = __shfl(A.x, src, 64);
    p.y = __shfl(A.y, src, 64);
    st.g<K>() = p;
    lanechain_impl<K+1>(st, src);
  }
}
__device__ __forceinline__ void cnot_lanechain(St& st, int t){
  const int lane = t & 63;
  const int w0 = (t >> 6) & 1;
  const int src = lane ^ ((lane >> 1) & 31) ^ (w0 << 5);
  lanechain_impl<0>(st, src);
}

// ---- ring q8: CNOT(c=l0, t=k5): conditional pairwise swap ----
template<int K>
__device__ __forceinline__ void q8_impl(St& st, bool ctrl){
  if constexpr (K < 32){
    constexpr int K1 = K | 32;
    float2 x0 = st.g<K>(), x1 = st.g<K1>();
    st.g<K>()  = ctrl ? x1 : x0;
    st.g<K1>() = ctrl ? x0 : x1;
    q8_impl<K+1>(st, ctrl);
  }
}

// ---- ring q9..q13: local ripple, pure compile-time register rename ----
template<int K>
__device__ __forceinline__ void ripple_impl(St& dst, St& src){
  if constexpr (K < NAMPS){
    dst.g<K>() = src.g<K ^ ((K>>1) & 31)>();
    ripple_impl<K+1>(dst, src);
  }
}

// ---- ring q14: CNOT(c=k0, t=w2): half-exchange of odd-k amps, partner t^256 ----
template<int K>
__device__ __forceinline__ void q14_w_impl(St& st, float2* xbuf, int t){
  if constexpr (K < 32){
    xbuf[K*BLOCK + t] = st.g<2*K + 1>();
    q14_w_impl<K+1>(st, xbuf, t);
  }
}
template<int K>
__device__ __forceinline__ void q14_r_impl(St& st, const float2* xbuf, int partner){
  if constexpr (K < 32){
    st.g<2*K + 1>() = xbuf[K*BLOCK + partner];
    q14_r_impl<K+1>(st, xbuf, partner);
  }
}
__device__ __forceinline__ void cnot_q14(St& st, int t, float2* xbuf){
  const int partner = t ^ 256;
  __syncthreads();
  q14_w_impl<0>(st, xbuf, t);
  __syncthreads();
  q14_r_impl<0>(st, xbuf, partner);
}

// ---- initial product state ----
template<int K>
__device__ __forceinline__ void init_impl(St& st, float hp,
                                          float lc0, float lc1, float lc2, float lc3, float lc4, float lc5,
                                          float ls0, float ls1, float ls2, float ls3, float ls4, float ls5){
  if constexpr (K < NAMPS){
    float v = hp;
    v *= (K & 32) ? ls5 : lc5;
    v *= (K & 16) ? ls4 : lc4;
    v *= (K & 8)  ? ls3 : lc3;
    v *= (K & 4)  ? ls2 : lc2;
    v *= (K & 2)  ? ls1 : lc1;
    v *= (K & 1)  ? ls0 : lc0;
    st.g<K>() = make_float2(v, 0.f);
    init_impl<K+1>(st, hp, lc0,lc1,lc2,lc3,lc4,lc5, ls0,ls1,ls2,ls3,ls4,ls5);
  }
}
template<int K>
__device__ __forceinline__ float sumsq_impl(St& st, float acc){
  if constexpr (K < NAMPS){
    float2 A = st.g<K>();
    return sumsq_impl<K+1>(st, acc + A.x*A.x + A.y*A.y);
  } else return acc;
}

__global__ __attribute__((amdgpu_flat_work_group_size(BLOCK,BLOCK), amdgpu_waves_per_eu(2,2)))
void qdarts_kernel(const float* __restrict__ x,     // [64,15]
                   const float* __restrict__ P,     // [4,15,1,4]
                   const float* __restrict__ Q,     // [4,15,4,3]
                   const float* __restrict__ rot,   // [60]
                   const float* __restrict__ gn,    // [4,15,3]
                   float* __restrict__ out)         // [64,4]
{
  __shared__ float2 xbuf[CHUNK * BLOCK];   // 128 KB exchange buffer
  __shared__ float  umat[60 * 8];          // 60 gate matrices
  __shared__ float  part[8];

  const int t    = threadIdx.x;
  const int b    = blockIdx.x;
  const int lane = t & 63;
  const int wave = t >> 6;

  // ---- 1. gate selection + matrices (one thread per (layer,qubit)) ----
  if (t < 60){
    const int idx = t;                         // idx = l*15 + q
    const float* Pv = P  + idx*4;
    const float* Qv = Q  + idx*12;
    const float* gv = gn + idx*3;
    int g = 0; float best = -1e30f;
    #pragma unroll
    for (int j = 0; j < 3; j++){
      float lg = Pv[0]*Qv[0*3+j] + Pv[1]*Qv[1*3+j] + Pv[2]*Qv[2*3+j] + Pv[3]*Qv[3*3+j] + gv[j];
      if (lg > best){ best = lg; g = j; }
    }
    const float half = rot[idx] * 0.5f;
    const float c = cosf(half), s = sinf(half);
    float m0,m1,m2,m3,m4,m5,m6,m7;
    if (g == 0){        // RX
      m0=c; m1=0.f; m2=0.f; m3=-s; m4=0.f; m5=-s; m6=c; m7=0.f;
    } else if (g == 1){ // RY
      m0=c; m1=0.f; m2=-s; m3=0.f; m4=s; m5=0.f; m6=c; m7=0.f;
    } else {            // RZ
      m0=c; m1=-s; m2=0.f; m3=0.f; m4=0.f; m5=0.f; m6=c; m7=s;
    }
    umat[idx*8+0]=m0; umat[idx*8+1]=m1; umat[idx*8+2]=m2; umat[idx*8+3]=m3;
    umat[idx*8+4]=m4; umat[idx*8+5]=m5; umat[idx*8+6]=m6; umat[idx*8+7]=m7;
  }
  __syncthreads();

  // ---- 2. initial state = RY-encoded product state (canonical layout) ----
  // m = (t<<6)|K ; q in [0,8] <-> t-bit (8-q); q in [9,14] <-> K-bit (14-q).
  const float* xb = x + b*15;
  float hp = 1.f;
  #pragma unroll
  for (int q = 0; q < 9; q++){
    const float h = xb[q]*0.5f;
    hp *= ((t >> (8-q)) & 1) ? sinf(h) : cosf(h);
  }
  float lc0,lc1,lc2,lc3,lc4,lc5, ls0,ls1,ls2,ls3,ls4,ls5;
  { float h;
    h = xb[14]*0.5f; lc0 = cosf(h); ls0 = sinf(h);
    h = xb[13]*0.5f; lc1 = cosf(h); ls1 = sinf(h);
    h = xb[12]*0.5f; lc2 = cosf(h); ls2 = sinf(h);
    h = xb[11]*0.5f; lc3 = cosf(h); ls3 = sinf(h);
    h = xb[10]*0.5f; lc4 = cosf(h); ls4 = sinf(h);
    h = xb[9] *0.5f; lc5 = cosf(h); ls5 = sinf(h);
  }
  St st;
  init_impl<0>(st, hp, lc0,lc1,lc2,lc3,lc4,lc5, ls0,ls1,ls2,ls3,ls4,ls5);

  // ---- 3. layers (canonical layout throughout; X1 used only around q3..q8 rotations) ----
  for (int l = 0; l < 4; l++){
    const float* U = umat + l*15*8;
    // rotations q9..q14 on canonical k-bits
    rot_local<5>(st, U + 9*8);     // q9  <-> k5
    rot_local<4>(st, U + 10*8);
    rot_local<3>(st, U + 11*8);
    rot_local<2>(st, U + 12*8);
    rot_local<1>(st, U + 13*8);
    rot_local<0>(st, U + 14*8);    // q14 <-> k0
    // X1 -> lane/reg swapped: reg bits now hold q3..q8 (K5=q3 .. K0=q8)
    x1_transpose(st, t, xbuf);
    rot_local<5>(st, U + 3*8);     // q3 <-> K5
    rot_local<4>(st, U + 4*8);
    rot_local<3>(st, U + 5*8);
    rot_local<2>(st, U + 6*8);
    rot_local<1>(st, U + 7*8);
    rot_local<0>(st, U + 8*8);     // q8 <-> K0
    // X1 back -> canonical
    x1_transpose(st, t, xbuf);
    // rotations q0,q1,q2 on wave bits
    rot_wave<2>(st, U + 0*8, t, xbuf);  // q0 <-> w2
    rot_wave<1>(st, U + 1*8, t, xbuf);  // q1 <-> w1
    rot_wave<0>(st, U + 2*8, t, xbuf);  // q2 <-> w0
    // CNOT ring in canonical layout (round-6 proven):
    cnot_wavechain(st, t, xbuf);                  // q0,q1 ; q1,q2
    cnot_lanechain(st, t);                        // q2..q7 (c=w0 then lane chain)
    q8_impl<0>(st, (bool)(lane & 1));             // q8: c=l0, t=k5
    { St tmp; ripple_impl<0>(tmp, st); st = tmp; } // q9..q13 (k-chain)
    cnot_q14(st, t, xbuf);                        // q14: c=k0, t=w2
  }

  // ---- 4. class probabilities: class = m[14:13] = wave>>1 ----
  float s = sumsq_impl<0>(st, 0.f);
  #pragma unroll
  for (int off = 32; off > 0; off >>= 1) s += __shfl_down(s, off, 64);
  if (lane == 0) part[wave] = s;
  __syncthreads();
  if (t < 4){
    out[b*4 + t] = part[2*t] + part[2*t+1];
  }
}

extern "C" void kernel_launch(void* const* d_in, const int* in_sizes, int n_in,
                              void* d_out, int out_size, void* d_ws, size_t ws_size,
                              hipStream_t stream) {
  const float* x   = (const float*)d_in[0];
  const float* P   = (const float*)d_in[1];
  const float* Q   = (const float*)d_in[2];
  const float* rot = (const float*)d_in[3];
  const float* gn  = (const float*)d_in[4];
  float* out = (float*)d_out;
  hipLaunchKernelGGL(qdarts_kernel, dim3(64), dim3(BLOCK), 0, stream,
                     x, P, Q, rot, gn, out);
}

// Round 9
// 1230.757 us; speedup vs baseline: 1.1789x; 1.1789x over previous
//
#include <hip/hip_runtime.h>

#define BLOCK 512    // 8 waves of 64
#define NAMPS 64     // amps per thread (128 VGPRs of state)
#define CHUNK 32     // regs per staging phase for wave-exchange ops

// ---------- state: 64 named float2 members, compile-time indexed ----------
struct St {
  float2 a0,a1,a2,a3,a4,a5,a6,a7,a8,a9,a10,a11,a12,a13,a14,a15,
         a16,a17,a18,a19,a20,a21,a22,a23,a24,a25,a26,a27,a28,a29,a30,a31,
         a32,a33,a34,a35,a36,a37,a38,a39,a40,a41,a42,a43,a44,a45,a46,a47,
         a48,a49,a50,a51,a52,a53,a54,a55,a56,a57,a58,a59,a60,a61,a62,a63;
  template<int I> __device__ __forceinline__ float2& g(){
    if constexpr (I==0) return a0;   else if constexpr (I==1) return a1;
    else if constexpr (I==2) return a2;   else if constexpr (I==3) return a3;
    else if constexpr (I==4) return a4;   else if constexpr (I==5) return a5;
    else if constexpr (I==6) return a6;   else if constexpr (I==7) return a7;
    else if constexpr (I==8) return a8;   else if constexpr (I==9) return a9;
    else if constexpr (I==10) return a10; else if constexpr (I==11) return a11;
    else if constexpr (I==12) return a12; else if constexpr (I==13) return a13;
    else if constexpr (I==14) return a14; else if constexpr (I==15) return a15;
    else if constexpr (I==16) return a16; else if constexpr (I==17) return a17;
    else if constexpr (I==18) return a18; else if constexpr (I==19) return a19;
    else if constexpr (I==20) return a20; else if constexpr (I==21) return a21;
    else if constexpr (I==22) return a22; else if constexpr (I==23) return a23;
    else if constexpr (I==24) return a24; else if constexpr (I==25) return a25;
    else if constexpr (I==26) return a26; else if constexpr (I==27) return a27;
    else if constexpr (I==28) return a28; else if constexpr (I==29) return a29;
    else if constexpr (I==30) return a30; else if constexpr (I==31) return a31;
    else if constexpr (I==32) return a32; else if constexpr (I==33) return a33;
    else if constexpr (I==34) return a34; else if constexpr (I==35) return a35;
    else if constexpr (I==36) return a36; else if constexpr (I==37) return a37;
    else if constexpr (I==38) return a38; else if constexpr (I==39) return a39;
    else if constexpr (I==40) return a40; else if constexpr (I==41) return a41;
    else if constexpr (I==42) return a42; else if constexpr (I==43) return a43;
    else if constexpr (I==44) return a44; else if constexpr (I==45) return a45;
    else if constexpr (I==46) return a46; else if constexpr (I==47) return a47;
    else if constexpr (I==48) return a48; else if constexpr (I==49) return a49;
    else if constexpr (I==50) return a50; else if constexpr (I==51) return a51;
    else if constexpr (I==52) return a52; else if constexpr (I==53) return a53;
    else if constexpr (I==54) return a54; else if constexpr (I==55) return a55;
    else if constexpr (I==56) return a56; else if constexpr (I==57) return a57;
    else if constexpr (I==58) return a58; else if constexpr (I==59) return a59;
    else if constexpr (I==60) return a60; else if constexpr (I==61) return a61;
    else if constexpr (I==62) return a62; else return a63;
  }
};

__device__ __forceinline__ float2 cmadd2(float2 u, float2 a, float2 v, float2 b){
  return make_float2(u.x*a.x - u.y*a.y + v.x*b.x - v.y*b.y,
                     u.x*a.y + u.y*a.x + v.x*b.y + v.y*b.x);
}

// ================= template-recursive gate bodies (all indices compile-time) =================

// ---- rotation on local k-bit BL (0..5) ----
template<int BL, int K>
__device__ __forceinline__ void rot_local_impl(St& st, float2 u00, float2 u01, float2 u10, float2 u11){
  if constexpr (K < NAMPS){
    if constexpr (!(K & (1<<BL))){
      constexpr int K1 = K | (1<<BL);
      float2 x0 = st.g<K>(), x1 = st.g<K1>();
      st.g<K>()  = cmadd2(u00, x0, u01, x1);
      st.g<K1>() = cmadd2(u10, x0, u11, x1);
    }
    rot_local_impl<BL, K+1>(st, u00, u01, u10, u11);
  }
}
template<int BL>
__device__ __forceinline__ void rot_local(St& st, const float* u){
  float2 u00 = make_float2(u[0],u[1]), u01 = make_float2(u[2],u[3]);
  float2 u10 = make_float2(u[4],u[5]), u11 = make_float2(u[6],u[7]);
  rot_local_impl<BL, 0>(st, u00, u01, u10, u11);
}

// ---- LDS staging helpers (compile-time chunk index) ----
template<int Base, int K>
__device__ __forceinline__ void stw_impl(St& st, float2* xbuf, int t){
  if constexpr (K < CHUNK){
    xbuf[K*BLOCK + t] = st.g<Base + K>();
    stw_impl<Base, K+1>(st, xbuf, t);
  }
}
template<int Base, int K>
__device__ __forceinline__ void ldr_rot_impl(St& st, const float2* xbuf, int partner, float2 ua, float2 ub){
  if constexpr (K < CHUNK){
    float2 p = xbuf[K*BLOCK + partner];
    float2 A = st.g<Base + K>();
    st.g<Base + K>() = cmadd2(ua, A, ub, p);
    ldr_rot_impl<Base, K+1>(st, xbuf, partner, ua, ub);
  }
}
template<int Base, int K>
__device__ __forceinline__ void ldr_mov_impl(St& st, const float2* xbuf, int src){
  if constexpr (K < CHUNK){
    st.g<Base + K>() = xbuf[K*BLOCK + src];
    ldr_mov_impl<Base, K+1>(st, xbuf, src);
  }
}

// ---- rotation on wave bit WB (0..2): LDS pair exchange, reg-phased ----
template<int WB>
__device__ __forceinline__ void rot_wave(St& st, const float* u, int t, float2* xbuf){
  const int partner = t ^ (64 << WB);
  const int bit = (t >> (6 + WB)) & 1;
  float2 u00 = make_float2(u[0],u[1]), u01 = make_float2(u[2],u[3]);
  float2 u10 = make_float2(u[4],u[5]), u11 = make_float2(u[6],u[7]);
  float2 ua = bit ? u11 : u00;
  float2 ub = bit ? u10 : u01;
  __syncthreads();                       // prior xbuf readers done
  stw_impl<0, 0>(st, xbuf, t);
  __syncthreads();
  ldr_rot_impl<0, 0>(st, xbuf, partner, ua, ub);
  __syncthreads();
  stw_impl<32, 0>(st, xbuf, t);
  __syncthreads();
  ldr_rot_impl<32, 0>(st, xbuf, partner, ua, ub);
}

// ---- X1: lane-bits <-> reg-bits transpose, immediate-offset addressing ----
// Per-wave region: 64 rows x 65 float2 (stride 520 B), region = 4160 float2.
// write: (row L, col K): base_w = region + L*65, element at +K   -> ds_write_b64 offset:8K
// read : (row K, col L): base_r = region + L,    element at +65K -> ds_read_b64 offset:520K
// New st.g<K>() of lane L = old st.g<L>() of lane K (exact lane/reg swap). Bijective slots.
template<int K>
__device__ __forceinline__ void x1_w_impl(St& st, float2* wbase){
  if constexpr (K < NAMPS){
    wbase[K] = st.g<K>();
    x1_w_impl<K+1>(st, wbase);
  }
}
template<int K>
__device__ __forceinline__ void x1_r_impl(St& st, const float2* rbase){
  if constexpr (K < NAMPS){
    st.g<K>() = rbase[65*K];
    x1_r_impl<K+1>(st, rbase);
  }
}
__device__ __forceinline__ void x1_transpose(St& st, int t, float2* xbuf){
  const int L = t & 63;
  const int W3 = (t >> 6) & 3;
  float2* wbase       = xbuf + W3*4160 + L*65;
  const float2* rbase = xbuf + W3*4160 + L;
  const bool grpA = (t < 256);     // waves 0-3, then 4-7 time-share the 4 regions
  __syncthreads();
  if (grpA)  x1_w_impl<0>(st, wbase);
  __syncthreads();
  if (grpA)  x1_r_impl<0>(st, rbase);
  __syncthreads();
  if (!grpA) x1_w_impl<0>(st, wbase);
  __syncthreads();
  if (!grpA) x1_r_impl<0>(st, rbase);
}

// ---- fused CNOT wave chain (c=w2,t=w1 then c=w1',t=w0): pure wave perm, reg-phased ----
__device__ __forceinline__ void cnot_wavechain(St& st, int t, float2* xbuf){
  const int wave = t >> 6, lane = t & 63;
  const int src = ((wave ^ ((wave >> 1) & 3)) << 6) | lane;
  __syncthreads();
  stw_impl<0, 0>(st, xbuf, t);
  __syncthreads();
  ldr_mov_impl<0, 0>(st, xbuf, src);
  __syncthreads();
  stw_impl<32, 0>(st, xbuf, t);
  __syncthreads();
  ldr_mov_impl<32, 0>(st, xbuf, src);
}

// ---- fused CNOT lane chain (q2..q7): one shuffle sweep; src = gray(lane) ^ (w0<<5) ----
template<int K>
__device__ __forceinline__ void lanechain_impl(St& st, int src){
  if constexpr (K < NAMPS){
    float2 A = st.g<K>();
    float2 p;
    p.x = __shfl(A.x, src, 64);
    p.y = __shfl(A.y, src, 64);
    st.g<K>() = p;
    lanechain_impl<K+1>(st, src);
  }
}
__device__ __forceinline__ void cnot_lanechain(St& st, int t){
  const int lane = t & 63;
  const int w0 = (t >> 6) & 1;
  const int src = lane ^ ((lane >> 1) & 31) ^ (w0 << 5);
  lanechain_impl<0>(st, src);
}

// ---- ring q8: CNOT(c=l0, t=k5): conditional pairwise swap ----
template<int K>
__device__ __forceinline__ void q8_impl(St& st, bool ctrl){
  if constexpr (K < 32){
    constexpr int K1 = K | 32;
    float2 x0 = st.g<K>(), x1 = st.g<K1>();
    st.g<K>()  = ctrl ? x1 : x0;
    st.g<K1>() = ctrl ? x0 : x1;
    q8_impl<K+1>(st, ctrl);
  }
}

// ---- ring q9..q13: local ripple, pure compile-time register rename ----
template<int K>
__device__ __forceinline__ void ripple_impl(St& dst, St& src){
  if constexpr (K < NAMPS){
    dst.g<K>() = src.g<K ^ ((K>>1) & 31)>();
    ripple_impl<K+1>(dst, src);
  }
}

// ---- ring q14: CNOT(c=k0, t=w2): half-exchange of odd-k amps, partner t^256 ----
template<int K>
__device__ __forceinline__ void q14_w_impl(St& st, float2* xbuf, int t){
  if constexpr (K < 32){
    xbuf[K*BLOCK + t] = st.g<2*K + 1>();
    q14_w_impl<K+1>(st, xbuf, t);
  }
}
template<int K>
__device__ __forceinline__ void q14_r_impl(St& st, const float2* xbuf, int partner){
  if constexpr (K < 32){
    st.g<2*K + 1>() = xbuf[K*BLOCK + partner];
    q14_r_impl<K+1>(st, xbuf, partner);
  }
}
__device__ __forceinline__ void cnot_q14(St& st, int t, float2* xbuf){
  const int partner = t ^ 256;
  __syncthreads();
  q14_w_impl<0>(st, xbuf, t);
  __syncthreads();
  q14_r_impl<0>(st, xbuf, partner);
}

// ---- initial product state ----
template<int K>
__device__ __forceinline__ void init_impl(St& st, float hp,
                                          float lc0, float lc1, float lc2, float lc3, float lc4, float lc5,
                                          float ls0, float ls1, float ls2, float ls3, float ls4, float ls5){
  if constexpr (K < NAMPS){
    float v = hp;
    v *= (K & 32) ? ls5 : lc5;
    v *= (K & 16) ? ls4 : lc4;
    v *= (K & 8)  ? ls3 : lc3;
    v *= (K & 4)  ? ls2 : lc2;
    v *= (K & 2)  ? ls1 : lc1;
    v *= (K & 1)  ? ls0 : lc0;
    st.g<K>() = make_float2(v, 0.f);
    init_impl<K+1>(st, hp, lc0,lc1,lc2,lc3,lc4,lc5, ls0,ls1,ls2,ls3,ls4,ls5);
  }
}
template<int K>
__device__ __forceinline__ float sumsq_impl(St& st, float acc){
  if constexpr (K < NAMPS){
    float2 A = st.g<K>();
    return sumsq_impl<K+1>(st, acc + A.x*A.x + A.y*A.y);
  } else return acc;
}

__global__ __attribute__((amdgpu_flat_work_group_size(BLOCK,BLOCK), amdgpu_waves_per_eu(2,2)))
void qdarts_kernel(const float* __restrict__ x,     // [64,15]
                   const float* __restrict__ P,     // [4,15,1,4]
                   const float* __restrict__ Q,     // [4,15,4,3]
                   const float* __restrict__ rot,   // [60]
                   const float* __restrict__ gn,    // [4,15,3]
                   float* __restrict__ out)         // [64,4]
{
  __shared__ float2 xbuf[16640];           // 130 KB: staging (16384) / X1 regions (4x4160)
  __shared__ float  umat[60 * 8];          // 60 gate matrices
  __shared__ float  part[8];

  const int t    = threadIdx.x;
  const int b    = blockIdx.x;
  const int lane = t & 63;
  const int wave = t >> 6;

  // ---- 1. gate selection + matrices (one thread per (layer,qubit)) ----
  if (t < 60){
    const int idx = t;                         // idx = l*15 + q
    const float* Pv = P  + idx*4;
    const float* Qv = Q  + idx*12;
    const float* gv = gn + idx*3;
    int g = 0; float best = -1e30f;
    #pragma unroll
    for (int j = 0; j < 3; j++){
      float lg = Pv[0]*Qv[0*3+j] + Pv[1]*Qv[1*3+j] + Pv[2]*Qv[2*3+j] + Pv[3]*Qv[3*3+j] + gv[j];
      if (lg > best){ best = lg; g = j; }
    }
    const float half = rot[idx] * 0.5f;
    const float c = cosf(half), s = sinf(half);
    float m0,m1,m2,m3,m4,m5,m6,m7;
    if (g == 0){        // RX
      m0=c; m1=0.f; m2=0.f; m3=-s; m4=0.f; m5=-s; m6=c; m7=0.f;
    } else if (g == 1){ // RY
      m0=c; m1=0.f; m2=-s; m3=0.f; m4=s; m5=0.f; m6=c; m7=0.f;
    } else {            // RZ
      m0=c; m1=-s; m2=0.f; m3=0.f; m4=0.f; m5=0.f; m6=c; m7=s;
    }
    umat[idx*8+0]=m0; umat[idx*8+1]=m1; umat[idx*8+2]=m2; umat[idx*8+3]=m3;
    umat[idx*8+4]=m4; umat[idx*8+5]=m5; umat[idx*8+6]=m6; umat[idx*8+7]=m7;
  }
  __syncthreads();

  // ---- 2. initial state = RY-encoded product state (canonical layout) ----
  // m = (t<<6)|K ; q in [0,8] <-> t-bit (8-q); q in [9,14] <-> K-bit (14-q).
  const float* xb = x + b*15;
  float hp = 1.f;
  #pragma unroll
  for (int q = 0; q < 9; q++){
    const float h = xb[q]*0.5f;
    hp *= ((t >> (8-q)) & 1) ? sinf(h) : cosf(h);
  }
  float lc0,lc1,lc2,lc3,lc4,lc5, ls0,ls1,ls2,ls3,ls4,ls5;
  { float h;
    h = xb[14]*0.5f; lc0 = cosf(h); ls0 = sinf(h);
    h = xb[13]*0.5f; lc1 = cosf(h); ls1 = sinf(h);
    h = xb[12]*0.5f; lc2 = cosf(h); ls2 = sinf(h);
    h = xb[11]*0.5f; lc3 = cosf(h); ls3 = sinf(h);
    h = xb[10]*0.5f; lc4 = cosf(h); ls4 = sinf(h);
    h = xb[9] *0.5f; lc5 = cosf(h); ls5 = sinf(h);
  }
  St st;
  init_impl<0>(st, hp, lc0,lc1,lc2,lc3,lc4,lc5, ls0,ls1,ls2,ls3,ls4,ls5);

  // ---- 3. layers (canonical layout; X1 only around q3..q8 rotations) ----
  for (int l = 0; l < 4; l++){
    const float* U = umat + l*15*8;
    // rotations q9..q14 on canonical k-bits
    rot_local<5>(st, U + 9*8);     // q9  <-> k5
    rot_local<4>(st, U + 10*8);
    rot_local<3>(st, U + 11*8);
    rot_local<2>(st, U + 12*8);
    rot_local<1>(st, U + 13*8);
    rot_local<0>(st, U + 14*8);    // q14 <-> k0
    // X1 -> lane/reg swapped: reg bits now hold q3..q8 (K5=q3 .. K0=q8)
    x1_transpose(st, t, xbuf);
    rot_local<5>(st, U + 3*8);     // q3 <-> K5
    rot_local<4>(st, U + 4*8);
    rot_local<3>(st, U + 5*8);
    rot_local<2>(st, U + 6*8);
    rot_local<1>(st, U + 7*8);
    rot_local<0>(st, U + 8*8);     // q8 <-> K0
    // X1 back -> canonical
    x1_transpose(st, t, xbuf);
    // rotations q0,q1,q2 on wave bits
    rot_wave<2>(st, U + 0*8, t, xbuf);  // q0 <-> w2
    rot_wave<1>(st, U + 1*8, t, xbuf);  // q1 <-> w1
    rot_wave<0>(st, U + 2*8, t, xbuf);  // q2 <-> w0
    // CNOT ring in canonical layout (round-6 proven):
    cnot_wavechain(st, t, xbuf);                  // q0,q1 ; q1,q2
    cnot_lanechain(st, t);                        // q2..q7 (c=w0 then lane chain)
    q8_impl<0>(st, (bool)(lane & 1));             // q8: c=l0, t=k5
    { St tmp; ripple_impl<0>(tmp, st); st = tmp; } // q9..q13 (k-chain)
    cnot_q14(st, t, xbuf);                        // q14: c=k0, t=w2
  }

  // ---- 4. class probabilities: class = m[14:13] = wave>>1 ----
  float s = sumsq_impl<0>(st, 0.f);
  #pragma unroll
  for (int off = 32; off > 0; off >>= 1) s += __shfl_down(s, off, 64);
  if (lane == 0) part[wave] = s;
  __syncthreads();
  if (t < 4){
    out[b*4 + t] = part[2*t] + part[2*t+1];
  }
}

extern "C" void kernel_launch(void* const* d_in, const int* in_sizes, int n_in,
                              void* d_out, int out_size, void* d_ws, size_t ws_size,
                              hipStream_t stream) {
  const float* x   = (const float*)d_in[0];
  const float* P   = (const float*)d_in[1];
  const float* Q   = (const float*)d_in[2];
  const float* rot = (const float*)d_in[3];
  const float* gn  = (const float*)d_in[4];
  float* out = (float*)d_out;
  hipLaunchKernelGGL(qdarts_kernel, dim3(64), dim3(BLOCK), 0, stream,
                     x, P, Q, rot, gn, out);
}

// Round 10
// 237.571 us; speedup vs baseline: 6.1072x; 5.1806x over previous
//
#include <hip/hip_runtime.h>

#define BLOCK 512    // 8 waves of 64
#define NAMPS 64     // amps per thread (128 VGPRs of state)
#define CHUNK 32     // regs per b64 staging phase (q14)

// ---------- state: 64 named float2 members, compile-time indexed ----------
struct St {
  float2 a0,a1,a2,a3,a4,a5,a6,a7,a8,a9,a10,a11,a12,a13,a14,a15,
         a16,a17,a18,a19,a20,a21,a22,a23,a24,a25,a26,a27,a28,a29,a30,a31,
         a32,a33,a34,a35,a36,a37,a38,a39,a40,a41,a42,a43,a44,a45,a46,a47,
         a48,a49,a50,a51,a52,a53,a54,a55,a56,a57,a58,a59,a60,a61,a62,a63;
  template<int I> __device__ __forceinline__ float2& g(){
    if constexpr (I==0) return a0;   else if constexpr (I==1) return a1;
    else if constexpr (I==2) return a2;   else if constexpr (I==3) return a3;
    else if constexpr (I==4) return a4;   else if constexpr (I==5) return a5;
    else if constexpr (I==6) return a6;   else if constexpr (I==7) return a7;
    else if constexpr (I==8) return a8;   else if constexpr (I==9) return a9;
    else if constexpr (I==10) return a10; else if constexpr (I==11) return a11;
    else if constexpr (I==12) return a12; else if constexpr (I==13) return a13;
    else if constexpr (I==14) return a14; else if constexpr (I==15) return a15;
    else if constexpr (I==16) return a16; else if constexpr (I==17) return a17;
    else if constexpr (I==18) return a18; else if constexpr (I==19) return a19;
    else if constexpr (I==20) return a20; else if constexpr (I==21) return a21;
    else if constexpr (I==22) return a22; else if constexpr (I==23) return a23;
    else if constexpr (I==24) return a24; else if constexpr (I==25) return a25;
    else if constexpr (I==26) return a26; else if constexpr (I==27) return a27;
    else if constexpr (I==28) return a28; else if constexpr (I==29) return a29;
    else if constexpr (I==30) return a30; else if constexpr (I==31) return a31;
    else if constexpr (I==32) return a32; else if constexpr (I==33) return a33;
    else if constexpr (I==34) return a34; else if constexpr (I==35) return a35;
    else if constexpr (I==36) return a36; else if constexpr (I==37) return a37;
    else if constexpr (I==38) return a38; else if constexpr (I==39) return a39;
    else if constexpr (I==40) return a40; else if constexpr (I==41) return a41;
    else if constexpr (I==42) return a42; else if constexpr (I==43) return a43;
    else if constexpr (I==44) return a44; else if constexpr (I==45) return a45;
    else if constexpr (I==46) return a46; else if constexpr (I==47) return a47;
    else if constexpr (I==48) return a48; else if constexpr (I==49) return a49;
    else if constexpr (I==50) return a50; else if constexpr (I==51) return a51;
    else if constexpr (I==52) return a52; else if constexpr (I==53) return a53;
    else if constexpr (I==54) return a54; else if constexpr (I==55) return a55;
    else if constexpr (I==56) return a56; else if constexpr (I==57) return a57;
    else if constexpr (I==58) return a58; else if constexpr (I==59) return a59;
    else if constexpr (I==60) return a60; else if constexpr (I==61) return a61;
    else if constexpr (I==62) return a62; else return a63;
  }
};

__device__ __forceinline__ float2 cmadd2(float2 u, float2 a, float2 v, float2 b){
  return make_float2(u.x*a.x - u.y*a.y + v.x*b.x - v.y*b.y,
                     u.x*a.y + u.y*a.x + v.x*b.y + v.y*b.x);
}

// ================= rotations =================

// ---- rotation on local k-bit BL (0..5) ----
template<int BL, int K>
__device__ __forceinline__ void rot_local_impl(St& st, float2 u00, float2 u01, float2 u10, float2 u11){
  if constexpr (K < NAMPS){
    if constexpr (!(K & (1<<BL))){
      constexpr int K1 = K | (1<<BL);
      float2 x0 = st.g<K>(), x1 = st.g<K1>();
      st.g<K>()  = cmadd2(u00, x0, u01, x1);
      st.g<K1>() = cmadd2(u10, x0, u11, x1);
    }
    rot_local_impl<BL, K+1>(st, u00, u01, u10, u11);
  }
}
template<int BL>
__device__ __forceinline__ void rot_local(St& st, const float* u){
  float2 u00 = make_float2(u[0],u[1]), u01 = make_float2(u[2],u[3]);
  float2 u10 = make_float2(u[4],u[5]), u11 = make_float2(u[6],u[7]);
  rot_local_impl<BL, 0>(st, u00, u01, u10, u11);
}

// ---- rotation on lane bit LB (2..5): wave shuffle (masks 4,8,16,32) ----
template<int LB, int K>
__device__ __forceinline__ void rot_lane_impl(St& st, float2 ua, float2 ub){
  if constexpr (K < NAMPS){
    float2 A = st.g<K>();
    float2 p;
    p.x = __shfl_xor(A.x, 1<<LB, 64);
    p.y = __shfl_xor(A.y, 1<<LB, 64);
    st.g<K>() = cmadd2(ua, A, ub, p);
    rot_lane_impl<LB, K+1>(st, ua, ub);
  }
}
template<int LB>
__device__ __forceinline__ void rot_lane(St& st, const float* u, int lane){
  const int bit = (lane >> LB) & 1;
  float2 u00 = make_float2(u[0],u[1]), u01 = make_float2(u[2],u[3]);
  float2 u10 = make_float2(u[4],u[5]), u11 = make_float2(u[6],u[7]);
  float2 ua = bit ? u11 : u00;
  float2 ub = bit ? u10 : u01;
  rot_lane_impl<LB, 0>(st, ua, ub);
}

// ---- rotation on lane bit 0/1 via DPP quad_perm (VALU, no DS pipe) ----
// xor1: quad_perm [1,0,3,2] = 0xB1 ; xor2: quad_perm [2,3,0,1] = 0x4E
template<int CTRL>
__device__ __forceinline__ float dppf(float v){
  int i = __float_as_int(v);
  return __int_as_float(__builtin_amdgcn_update_dpp(i, i, CTRL, 0xF, 0xF, false));
}
template<int CTRL, int K>
__device__ __forceinline__ void rot_dpp_impl(St& st, float2 ua, float2 ub){
  if constexpr (K < NAMPS){
    float2 A = st.g<K>();
    float2 p = make_float2(dppf<CTRL>(A.x), dppf<CTRL>(A.y));
    st.g<K>() = cmadd2(ua, A, ub, p);
    rot_dpp_impl<CTRL, K+1>(st, ua, ub);
  }
}
template<int LB, int CTRL>
__device__ __forceinline__ void rot_dpp(St& st, const float* u, int lane){
  const int bit = (lane >> LB) & 1;
  float2 u00 = make_float2(u[0],u[1]), u01 = make_float2(u[2],u[3]);
  float2 u10 = make_float2(u[4],u[5]), u11 = make_float2(u[6],u[7]);
  float2 ua = bit ? u11 : u00;
  float2 ub = bit ? u10 : u01;
  rot_dpp_impl<CTRL, 0>(st, ua, ub);
}

// ================= b128-packed staging (layout: float4 xb4[K2*BLOCK + t]) =================
template<int Base, int K2>
__device__ __forceinline__ void stw128_impl(St& st, float4* xb4, int t){
  if constexpr (K2 < 16){
    float2 a = st.g<Base + 2*K2>(), b = st.g<Base + 2*K2 + 1>();
    xb4[K2*BLOCK + t] = make_float4(a.x, a.y, b.x, b.y);
    stw128_impl<Base, K2+1>(st, xb4, t);
  }
}
template<int Base, int K2>
__device__ __forceinline__ void ldr128_rot_impl(St& st, const float4* xb4, int partner, float2 ua, float2 ub){
  if constexpr (K2 < 16){
    float4 p = xb4[K2*BLOCK + partner];
    float2 A = st.g<Base + 2*K2>(), B = st.g<Base + 2*K2 + 1>();
    st.g<Base + 2*K2>()     = cmadd2(ua, A, ub, make_float2(p.x, p.y));
    st.g<Base + 2*K2 + 1>() = cmadd2(ua, B, ub, make_float2(p.z, p.w));
    ldr128_rot_impl<Base, K2+1>(st, xb4, partner, ua, ub);
  }
}
// fused read: out = ua*X[s] + ub*X[s2]  (both operands from LDS)
template<int Base, int K2>
__device__ __forceinline__ void fread_impl(St& st, const float4* xb4, int s, int s2, float2 ua, float2 ub){
  if constexpr (K2 < 16){
    float4 p = xb4[K2*BLOCK + s];
    float4 q = xb4[K2*BLOCK + s2];
    st.g<Base + 2*K2>()     = cmadd2(ua, make_float2(p.x,p.y), ub, make_float2(q.x,q.y));
    st.g<Base + 2*K2 + 1>() = cmadd2(ua, make_float2(p.z,p.w), ub, make_float2(q.z,q.w));
    fread_impl<Base, K2+1>(st, xb4, s, s2, ua, ub);
  }
}

// ---- rotation on wave bit WB (1..2): b128 LDS pair exchange ----
template<int WB>
__device__ __forceinline__ void rot_wave(St& st, const float* u, int t, float4* xb4){
  const int partner = t ^ (64 << WB);
  const int bit = (t >> (6 + WB)) & 1;
  float2 u00 = make_float2(u[0],u[1]), u01 = make_float2(u[2],u[3]);
  float2 u10 = make_float2(u[4],u[5]), u11 = make_float2(u[6],u[7]);
  float2 ua = bit ? u11 : u00;
  float2 ub = bit ? u10 : u01;
  __syncthreads();                       // prior xbuf readers done
  stw128_impl<0, 0>(st, xb4, t);
  __syncthreads();
  ldr128_rot_impl<0, 0>(st, xb4, partner, ua, ub);
  __syncthreads();
  stw128_impl<32, 0>(st, xb4, t);
  __syncthreads();
  ldr128_rot_impl<32, 0>(st, xb4, partner, ua, ub);
}

// ---- FUSED: rotation q2 (wave bit 0) + CNOT wavechain (q0,q1) ----
// final[t] = RotOut[s], s = perm(t);  RotOut[x] = ua(x6)*X[x] + ub(x6)*X[x^64]
__device__ __forceinline__ void rotq2_wavechain(St& st, const float* u, int t, float4* xb4){
  const int wave = t >> 6, lane = t & 63;
  const int s  = ((wave ^ ((wave >> 1) & 3)) << 6) | lane;
  const int s2 = s ^ 64;
  const int sbit = (s >> 6) & 1;
  float2 u00 = make_float2(u[0],u[1]), u01 = make_float2(u[2],u[3]);
  float2 u10 = make_float2(u[4],u[5]), u11 = make_float2(u[6],u[7]);
  float2 ua = sbit ? u11 : u00;
  float2 ub = sbit ? u10 : u01;
  __syncthreads();
  stw128_impl<0, 0>(st, xb4, t);
  __syncthreads();
  fread_impl<0, 0>(st, xb4, s, s2, ua, ub);
  __syncthreads();
  stw128_impl<32, 0>(st, xb4, t);
  __syncthreads();
  fread_impl<32, 0>(st, xb4, s, s2, ua, ub);
}

// ---- fused CNOT lane chain (q2..q7): one shuffle sweep; src = gray(lane) ^ (w0<<5) ----
template<int K>
__device__ __forceinline__ void lanechain_impl(St& st, int src){
  if constexpr (K < NAMPS){
    float2 A = st.g<K>();
    float2 p;
    p.x = __shfl(A.x, src, 64);
    p.y = __shfl(A.y, src, 64);
    st.g<K>() = p;
    lanechain_impl<K+1>(st, src);
  }
}
__device__ __forceinline__ void cnot_lanechain(St& st, int t){
  const int lane = t & 63;
  const int w0 = (t >> 6) & 1;
  const int src = lane ^ ((lane >> 1) & 31) ^ (w0 << 5);
  lanechain_impl<0>(st, src);
}

// ---- ring q8: CNOT(c=l0, t=k5): conditional pairwise swap ----
template<int K>
__device__ __forceinline__ void q8_impl(St& st, bool ctrl){
  if constexpr (K < 32){
    constexpr int K1 = K | 32;
    float2 x0 = st.g<K>(), x1 = st.g<K1>();
    st.g<K>()  = ctrl ? x1 : x0;
    st.g<K1>() = ctrl ? x0 : x1;
    q8_impl<K+1>(st, ctrl);
  }
}

// ---- ring q9..q13: local ripple, pure compile-time register rename ----
template<int K>
__device__ __forceinline__ void ripple_impl(St& dst, St& src){
  if constexpr (K < NAMPS){
    dst.g<K>() = src.g<K ^ ((K>>1) & 31)>();
    ripple_impl<K+1>(dst, src);
  }
}

// ---- ring q14: CNOT(c=k0, t=w2): half-exchange of odd-k amps, partner t^256 (b64) ----
template<int K>
__device__ __forceinline__ void q14_w_impl(St& st, float2* xb2, int t){
  if constexpr (K < 32){
    xb2[K*BLOCK + t] = st.g<2*K + 1>();
    q14_w_impl<K+1>(st, xb2, t);
  }
}
template<int K>
__device__ __forceinline__ void q14_r_impl(St& st, const float2* xb2, int partner){
  if constexpr (K < 32){
    st.g<2*K + 1>() = xb2[K*BLOCK + partner];
    q14_r_impl<K+1>(st, xb2, partner);
  }
}
__device__ __forceinline__ void cnot_q14(St& st, int t, float2* xb2){
  const int partner = t ^ 256;
  __syncthreads();
  q14_w_impl<0>(st, xb2, t);
  __syncthreads();
  q14_r_impl<0>(st, xb2, partner);
}

// ---- initial product state ----
template<int K>
__device__ __forceinline__ void init_impl(St& st, float hp,
                                          float lc0, float lc1, float lc2, float lc3, float lc4, float lc5,
                                          float ls0, float ls1, float ls2, float ls3, float ls4, float ls5){
  if constexpr (K < NAMPS){
    float v = hp;
    v *= (K & 32) ? ls5 : lc5;
    v *= (K & 16) ? ls4 : lc4;
    v *= (K & 8)  ? ls3 : lc3;
    v *= (K & 4)  ? ls2 : lc2;
    v *= (K & 2)  ? ls1 : lc1;
    v *= (K & 1)  ? ls0 : lc0;
    st.g<K>() = make_float2(v, 0.f);
    init_impl<K+1>(st, hp, lc0,lc1,lc2,lc3,lc4,lc5, ls0,ls1,ls2,ls3,ls4,ls5);
  }
}
template<int K>
__device__ __forceinline__ float sumsq_impl(St& st, float acc){
  if constexpr (K < NAMPS){
    float2 A = st.g<K>();
    return sumsq_impl<K+1>(st, acc + A.x*A.x + A.y*A.y);
  } else return acc;
}

__global__ __attribute__((amdgpu_flat_work_group_size(BLOCK,BLOCK), amdgpu_waves_per_eu(2,2)))
void qdarts_kernel(const float* __restrict__ x,     // [64,15]
                   const float* __restrict__ P,     // [4,15,1,4]
                   const float* __restrict__ Q,     // [4,15,4,3]
                   const float* __restrict__ rot,   // [60]
                   const float* __restrict__ gn,    // [4,15,3]
                   float* __restrict__ out)         // [64,4]
{
  __shared__ float4 xb4[16 * BLOCK];       // 128 KB exchange buffer (b128 layout)
  __shared__ float  umat[60 * 8];          // 60 gate matrices
  __shared__ float  part[8];
  float2* xb2 = reinterpret_cast<float2*>(xb4);   // b64 view for q14

  const int t    = threadIdx.x;
  const int b    = blockIdx.x;
  const int lane = t & 63;
  const int wave = t >> 6;

  // ---- 1. gate selection + matrices (one thread per (layer,qubit)) ----
  if (t < 60){
    const int idx = t;                         // idx = l*15 + q
    const float* Pv = P  + idx*4;
    const float* Qv = Q  + idx*12;
    const float* gv = gn + idx*3;
    int g = 0; float best = -1e30f;
    #pragma unroll
    for (int j = 0; j < 3; j++){
      float lg = Pv[0]*Qv[0*3+j] + Pv[1]*Qv[1*3+j] + Pv[2]*Qv[2*3+j] + Pv[3]*Qv[3*3+j] + gv[j];
      if (lg > best){ best = lg; g = j; }
    }
    const float half = rot[idx] * 0.5f;
    const float c = cosf(half), s = sinf(half);
    float m0,m1,m2,m3,m4,m5,m6,m7;
    if (g == 0){        // RX
      m0=c; m1=0.f; m2=0.f; m3=-s; m4=0.f; m5=-s; m6=c; m7=0.f;
    } else if (g == 1){ // RY
      m0=c; m1=0.f; m2=-s; m3=0.f; m4=s; m5=0.f; m6=c; m7=0.f;
    } else {            // RZ
      m0=c; m1=-s; m2=0.f; m3=0.f; m4=0.f; m5=0.f; m6=c; m7=s;
    }
    umat[idx*8+0]=m0; umat[idx*8+1]=m1; umat[idx*8+2]=m2; umat[idx*8+3]=m3;
    umat[idx*8+4]=m4; umat[idx*8+5]=m5; umat[idx*8+6]=m6; umat[idx*8+7]=m7;
  }
  __syncthreads();

  // ---- 2. initial state = RY-encoded product state (canonical layout) ----
  // m = (t<<6)|K ; q in [0,8] <-> t-bit (8-q); q in [9,14] <-> K-bit (14-q).
  const float* xb = x + b*15;
  float hp = 1.f;
  #pragma unroll
  for (int q = 0; q < 9; q++){
    const float h = xb[q]*0.5f;
    hp *= ((t >> (8-q)) & 1) ? sinf(h) : cosf(h);
  }
  float lc0,lc1,lc2,lc3,lc4,lc5, ls0,ls1,ls2,ls3,ls4,ls5;
  { float h;
    h = xb[14]*0.5f; lc0 = cosf(h); ls0 = sinf(h);
    h = xb[13]*0.5f; lc1 = cosf(h); ls1 = sinf(h);
    h = xb[12]*0.5f; lc2 = cosf(h); ls2 = sinf(h);
    h = xb[11]*0.5f; lc3 = cosf(h); ls3 = sinf(h);
    h = xb[10]*0.5f; lc4 = cosf(h); ls4 = sinf(h);
    h = xb[9] *0.5f; lc5 = cosf(h); ls5 = sinf(h);
  }
  St st;
  init_impl<0>(st, hp, lc0,lc1,lc2,lc3,lc4,lc5, ls0,ls1,ls2,ls3,ls4,ls5);

  // ---- 3. layers (canonical layout; round-6 structure + DPP + b128 + fusion) ----
  for (int l = 0; l < 4; l++){
    const float* U = umat + l*15*8;
    // rotations q9..q14 on k-bits (in-register)
    rot_local<5>(st, U + 9*8);     // q9  <-> k5
    rot_local<4>(st, U + 10*8);
    rot_local<3>(st, U + 11*8);
    rot_local<2>(st, U + 12*8);
    rot_local<1>(st, U + 13*8);
    rot_local<0>(st, U + 14*8);    // q14 <-> k0
    // rotations q3..q6 on lane bits 5..2 (shuffle), q7/q8 via DPP quad_perm
    rot_lane<5>(st, U + 3*8, lane);         // q3, mask 32
    rot_lane<4>(st, U + 4*8, lane);         // q4, mask 16
    rot_lane<3>(st, U + 5*8, lane);         // q5, mask 8
    rot_lane<2>(st, U + 6*8, lane);         // q6, mask 4
    rot_dpp<1, 0x4E>(st, U + 7*8, lane);    // q7, mask 2 (quad_perm [2,3,0,1])
    rot_dpp<0, 0xB1>(st, U + 8*8, lane);    // q8, mask 1 (quad_perm [1,0,3,2])
    // rotations q0,q1 on wave bits (b128-staged)
    rot_wave<2>(st, U + 0*8, t, xb4);       // q0 <-> w2
    rot_wave<1>(st, U + 1*8, t, xb4);       // q1 <-> w1
    // q2 rotation fused with CNOT q0,q1 wavechain
    rotq2_wavechain(st, U + 2*8, t, xb4);
    // rest of CNOT ring (round-6 proven):
    cnot_lanechain(st, t);                        // q2..q7 (c=w0 then lane chain)
    q8_impl<0>(st, (bool)(lane & 1));             // q8: c=l0, t=k5
    { St tmp; ripple_impl<0>(tmp, st); st = tmp; } // q9..q13 (k-chain)
    cnot_q14(st, t, xb2);                         // q14: c=k0, t=w2
  }

  // ---- 4. class probabilities: class = m[14:13] = wave>>1 ----
  float s = sumsq_impl<0>(st, 0.f);
  #pragma unroll
  for (int off = 32; off > 0; off >>= 1) s += __shfl_down(s, off, 64);
  if (lane == 0) part[wave] = s;
  __syncthreads();
  if (t < 4){
    out[b*4 + t] = part[2*t] + part[2*t+1];
  }
}

extern "C" void kernel_launch(void* const* d_in, const int* in_sizes, int n_in,
                              void* d_out, int out_size, void* d_ws, size_t ws_size,
                              hipStream_t stream) {
  const float* x   = (const float*)d_in[0];
  const float* P   = (const float*)d_in[1];
  const float* Q   = (const float*)d_in[2];
  const float* rot = (const float*)d_in[3];
  const float* gn  = (const float*)d_in[4];
  float* out = (float*)d_out;
  hipLaunchKernelGGL(qdarts_kernel, dim3(64), dim3(BLOCK), 0, stream,
                     x, P, Q, rot, gn, out);
}